// Round 1
// baseline (283.210 us; speedup 1.0000x reference)
//
#include <hip/hip_runtime.h>

// SelfAttention3d: B=4, C=128, D=16, H=W=64.
// Pipeline (all bf16 MFMA compute, f32 accum/softmax):
//   K1 conv qkv (fused, reads x f32)   : q -> ws, k -> d_out[0:64M], v -> d_out[64M:128M]  (bf16)
//   K2 attention per (b,c,d) 64x64     : O -> ws (in-place over q)
//   K3 conv a1 + relu (in-place ws)
//   K4 conv a2        (in-place ws)
//   K5 conv f  -> d_out (f32, overwrites dead k/v scratch)

#define CCH 128
#define SPB 65536      // per-batch spatial = D*H*W = 16*64*64
#define NBATCH 4

typedef float f32x4 __attribute__((ext_vector_type(4)));
typedef __bf16 bf16x8 __attribute__((ext_vector_type(8)));
typedef short s16x8 __attribute__((ext_vector_type(8)));
typedef unsigned short u16x8 __attribute__((ext_vector_type(8)));
typedef unsigned short u16x4 __attribute__((ext_vector_type(4)));

// ---- MFMA wrapper: robust to builtin signature (v8i16 vs v8bf16) ----
template <typename T>
static __device__ __forceinline__ auto mfma_try(T a, T b, f32x4 c, int)
    -> decltype(__builtin_amdgcn_mfma_f32_16x16x32_bf16(a, b, c, 0, 0, 0)) {
  return __builtin_amdgcn_mfma_f32_16x16x32_bf16(a, b, c, 0, 0, 0);
}
template <typename T>
static __device__ __forceinline__ f32x4 mfma_try(T a, T b, f32x4 c, long) {
  return __builtin_amdgcn_mfma_f32_16x16x32_bf16(
      __builtin_bit_cast(bf16x8, a), __builtin_bit_cast(bf16x8, b), c, 0, 0, 0);
}
static __device__ __forceinline__ f32x4 MFMA16(u16x8 a, u16x8 b, f32x4 c) {
  return mfma_try(__builtin_bit_cast(s16x8, a), __builtin_bit_cast(s16x8, b), c, 0);
}

// f32 -> bf16 bits, round-to-nearest-even
static __device__ __forceinline__ unsigned short f2b(float f) {
  unsigned int u = __builtin_bit_cast(unsigned int, f);
  u += 0x7FFFu + ((u >> 16) & 1u);
  return (unsigned short)(u >> 16);
}

// XOR swizzle (G4): spread 16B column reads of row-major tiles across banks.
// Element-index form: c ^ ((r&7)<<3) swaps 8-element (16B) groups.
static __device__ __forceinline__ int swz128(int r, int c) {  // row length 128
  return r * 128 + (c ^ ((r & 7) << 3));
}
static __device__ __forceinline__ int swz64(int r, int c) {   // row length 64
  return r * 64 + (c ^ ((r & 7) << 3));
}

// ---------------------------------------------------------------------------
// conv1x1: Y[b,o,s] = sum_c W[o,c] * X[b,c,s] + bias[o]   (optionally relu)
// Tile: M=128 (all out-ch), N=128 spatial, K=128 (all in-ch). 256 thr / 4 waves.
// Wave wv owns N-range [wv*32, wv*32+32): 8 M-frags x 2 N-frags, K-loop of 4.
// ---------------------------------------------------------------------------
template <bool IN_F32, bool OUT_F32, bool RELU, int NOUT>
__global__ __launch_bounds__(256) void conv1x1_kernel(
    const void* __restrict__ Xv,
    const float* __restrict__ W0, const float* __restrict__ B0, void* __restrict__ Y0,
    const float* __restrict__ W1, const float* __restrict__ B1, void* __restrict__ Y1,
    const float* __restrict__ W2, const float* __restrict__ B2, void* __restrict__ Y2)
{
  __shared__ unsigned short w_lds[128 * 128];   // W[o][c]  (A operand, row=o, k=c)
  __shared__ unsigned short xt_lds[128 * 128];  // X^T[s_local][c] (B operand, row=n, k=c)
  __shared__ float bias_lds[128];

  const int tid  = threadIdx.x;
  const int wv   = tid >> 6;
  const int lane = tid & 63;
  const int lr   = lane & 15;
  const int lg   = lane >> 4;
  const int s0   = blockIdx.x * 128;
  const int b    = blockIdx.y;
  const size_t xbase = (size_t)b * CCH * SPB;

  // ---- stage X tile transposed into LDS (coalesced global read, bf16) ----
  {
    const int rr = tid >> 5;          // 0..7
    const int cg = (tid & 31) << 2;   // s_local group: 0,4,...,124
#pragma unroll
    for (int p = 0; p < 16; ++p) {
      const int c = p * 8 + rr;       // channel 0..127
      unsigned short u[4];
      if (IN_F32) {
        const float* X = (const float*)Xv;
        f32x4 xv = *(const f32x4*)&X[xbase + (size_t)c * SPB + s0 + cg];
        u[0] = f2b(xv[0]); u[1] = f2b(xv[1]); u[2] = f2b(xv[2]); u[3] = f2b(xv[3]);
      } else {
        const unsigned short* X = (const unsigned short*)Xv;
        u16x4 xv = *(const u16x4*)&X[xbase + (size_t)c * SPB + s0 + cg];
        u[0] = xv[0]; u[1] = xv[1]; u[2] = xv[2]; u[3] = xv[3];
      }
#pragma unroll
      for (int i = 0; i < 4; ++i) xt_lds[swz128(cg + i, c)] = u[i];
    }
  }

  auto do_conv = [&](const float* __restrict__ W, const float* __restrict__ Bb,
                     void* __restrict__ Y) {
    __syncthreads();  // X staged (j=0) / previous GEMM's LDS reads done (j>0)
    // ---- stage W (f32 -> bf16), natural [o][c] layout ----
    {
      const int rr = tid >> 5;
      const int cg = (tid & 31) << 2;
#pragma unroll
      for (int p = 0; p < 16; ++p) {
        const int m = p * 8 + rr;
        f32x4 wv4 = *(const f32x4*)&W[m * 128 + cg];
#pragma unroll
        for (int i = 0; i < 4; ++i) w_lds[swz128(m, cg + i)] = f2b(wv4[i]);
      }
      if (tid < 128) bias_lds[tid] = Bb[tid];
    }
    __syncthreads();

    f32x4 acc[8][2];
#pragma unroll
    for (int mf = 0; mf < 8; ++mf)
#pragma unroll
      for (int nf = 0; nf < 2; ++nf) {
        f32x4 z = {0.f, 0.f, 0.f, 0.f};
        acc[mf][nf] = z;
      }

#pragma unroll
    for (int ks = 0; ks < 4; ++ks) {
      const int k0 = ks * 32 + lg * 8;
      u16x8 bfr[2];
#pragma unroll
      for (int nf = 0; nf < 2; ++nf) {
        const int n = wv * 32 + nf * 16 + lr;
        bfr[nf] = *(const u16x8*)&xt_lds[swz128(n, k0)];
      }
#pragma unroll
      for (int mf = 0; mf < 8; ++mf) {
        const int m = mf * 16 + lr;
        u16x8 afr = *(const u16x8*)&w_lds[swz128(m, k0)];
        acc[mf][0] = MFMA16(afr, bfr[0], acc[mf][0]);
        acc[mf][1] = MFMA16(afr, bfr[1], acc[mf][1]);
      }
    }

    // ---- epilogue: D row = lg*4+r, col = lr ----
#pragma unroll
    for (int mf = 0; mf < 8; ++mf)
#pragma unroll
      for (int nf = 0; nf < 2; ++nf)
#pragma unroll
        for (int r = 0; r < 4; ++r) {
          const int o = mf * 16 + lg * 4 + r;
          const int s = s0 + wv * 32 + nf * 16 + lr;
          float val = acc[mf][nf][r] + bias_lds[o];
          if (RELU) val = fmaxf(val, 0.f);
          if (OUT_F32)
            ((float*)Y)[xbase + (size_t)o * SPB + s] = val;
          else
            ((unsigned short*)Y)[xbase + (size_t)o * SPB + s] = f2b(val);
        }
  };

  do_conv(W0, B0, Y0);
  if constexpr (NOUT > 1) do_conv(W1, B1, Y1);
  if constexpr (NOUT > 2) do_conv(W2, B2, Y2);
}

// ---------------------------------------------------------------------------
// attention over one (b,c,d) slice: S[i,j] = sum_x Q[x,i] K[x,j];
// P = softmax_j(S); O[i,j] = sum_k P[i,k] V[k,j].
// Tiles are the contiguous 64x64 (h,w) blocks of q/k/v. 1 WG (4 waves)/slice.
// Wave wv owns rows i in [wv*16, wv*16+16).
// ---------------------------------------------------------------------------
__global__ __launch_bounds__(256) void attn64_kernel(
    const unsigned short* __restrict__ Q,
    const unsigned short* __restrict__ K,
    const unsigned short* __restrict__ V,
    unsigned short* __restrict__ O)
{
  __shared__ unsigned short qt[64 * 64];      // Q^T[i(w)][x(h)]
  __shared__ unsigned short kt[64 * 64];      // K^T[j(w)][x(h)]
  __shared__ unsigned short vt[64 * 64];      // V^T[j(w)][k(h)]
  __shared__ unsigned short p_lds[4][16 * 64];

  const int tid  = threadIdx.x;
  const int wv   = tid >> 6;
  const int lane = tid & 63;
  const int lr   = lane & 15;
  const int lg   = lane >> 4;
  const size_t base = (size_t)blockIdx.x * 4096;

  // ---- stage Q,K,V transposed (coalesced 16B global reads, 2B LDS writes) ----
  {
    const int x  = tid >> 2;          // h row 0..63
    const int w0 = (tid & 3) << 4;    // w col group
#pragma unroll
    for (int hh = 0; hh < 2; ++hh) {
      const size_t g = base + (size_t)x * 64 + w0 + hh * 8;
      u16x8 qv = *(const u16x8*)&Q[g];
      u16x8 kv = *(const u16x8*)&K[g];
      u16x8 vv = *(const u16x8*)&V[g];
#pragma unroll
      for (int i = 0; i < 8; ++i) {
        const int wc = w0 + hh * 8 + i;
        qt[swz64(wc, x)] = qv[i];
        kt[swz64(wc, x)] = kv[i];
        vt[swz64(wc, x)] = vv[i];
      }
    }
  }
  __syncthreads();

  // ---- S = Q^T K ----
  f32x4 sacc[4];
#pragma unroll
  for (int nf = 0; nf < 4; ++nf) { f32x4 z = {0.f, 0.f, 0.f, 0.f}; sacc[nf] = z; }
#pragma unroll
  for (int ks = 0; ks < 2; ++ks) {
    const int k0 = ks * 32 + lg * 8;
    u16x8 a = *(const u16x8*)&qt[swz64(wv * 16 + lr, k0)];
#pragma unroll
    for (int nf = 0; nf < 4; ++nf) {
      u16x8 bb = *(const u16x8*)&kt[swz64(nf * 16 + lr, k0)];
      sacc[nf] = MFMA16(a, bb, sacc[nf]);
    }
  }

  // ---- softmax over j (row = wv*16 + lg*4 + r spread over the 16 lr-lanes) ----
#pragma unroll
  for (int r = 0; r < 4; ++r) {
    float m = fmaxf(fmaxf(sacc[0][r], sacc[1][r]), fmaxf(sacc[2][r], sacc[3][r]));
    m = fmaxf(m, __shfl_xor(m, 1));
    m = fmaxf(m, __shfl_xor(m, 2));
    m = fmaxf(m, __shfl_xor(m, 4));
    m = fmaxf(m, __shfl_xor(m, 8));
    float sum = 0.f;
#pragma unroll
    for (int nf = 0; nf < 4; ++nf) {
      float p = __expf(sacc[nf][r] - m);
      sacc[nf][r] = p;
      sum += p;
    }
    sum += __shfl_xor(sum, 1);
    sum += __shfl_xor(sum, 2);
    sum += __shfl_xor(sum, 4);
    sum += __shfl_xor(sum, 8);
    const float inv = 1.f / sum;
#pragma unroll
    for (int nf = 0; nf < 4; ++nf)
      p_lds[wv][swz64(lg * 4 + r, nf * 16 + lr)] = f2b(sacc[nf][r] * inv);
  }
  // p_lds region is wave-private; in-wave LDS write->read ordering is handled
  // by compiler-inserted lgkmcnt. No barrier needed.

  // ---- O = P V ----
  f32x4 oacc[4];
#pragma unroll
  for (int nf = 0; nf < 4; ++nf) { f32x4 z = {0.f, 0.f, 0.f, 0.f}; oacc[nf] = z; }
#pragma unroll
  for (int ks = 0; ks < 2; ++ks) {
    const int k0 = ks * 32 + lg * 8;
    u16x8 a = *(const u16x8*)&p_lds[wv][swz64(lr, k0)];
#pragma unroll
    for (int nf = 0; nf < 4; ++nf) {
      u16x8 bb = *(const u16x8*)&vt[swz64(nf * 16 + lr, k0)];
      oacc[nf] = MFMA16(a, bb, oacc[nf]);
    }
  }
#pragma unroll
  for (int nf = 0; nf < 4; ++nf)
#pragma unroll
    for (int r = 0; r < 4; ++r)
      O[base + (size_t)(wv * 16 + lg * 4 + r) * 64 + nf * 16 + lr] = f2b(oacc[nf][r]);
}

extern "C" void kernel_launch(void* const* d_in, const int* in_sizes, int n_in,
                              void* d_out, int out_size, void* d_ws, size_t ws_size,
                              hipStream_t stream) {
  const float* x   = (const float*)d_in[0];
  const float* Wq  = (const float*)d_in[1];  const float* bq  = (const float*)d_in[2];
  const float* Wk  = (const float*)d_in[3];  const float* bk  = (const float*)d_in[4];
  const float* Wv  = (const float*)d_in[5];  const float* bv  = (const float*)d_in[6];
  const float* Wa1 = (const float*)d_in[7];  const float* ba1 = (const float*)d_in[8];
  const float* Wa2 = (const float*)d_in[9];  const float* ba2 = (const float*)d_in[10];
  const float* Wf  = (const float*)d_in[11]; const float* bf_ = (const float*)d_in[12];

  // bf16 scratch: q in ws; k,v packed into d_out (dead before final f32 write).
  unsigned short* qb = (unsigned short*)d_ws;
  unsigned short* kb = (unsigned short*)d_out;
  unsigned short* vb = kb + (size_t)NBATCH * CCH * SPB;

  dim3 grid(SPB / 128, NBATCH);

  // K1: fused qkv
  conv1x1_kernel<true, false, false, 3><<<grid, 256, 0, stream>>>(
      x, Wq, bq, qb, Wk, bk, kb, Wv, bv, vb);

  // K2: attention, O overwrites q in-place (slice staged to LDS before write)
  attn64_kernel<<<NBATCH * CCH * 16, 256, 0, stream>>>(qb, kb, vb, qb);

  // K3: a1 + relu (in-place in ws)
  conv1x1_kernel<false, false, true, 1><<<grid, 256, 0, stream>>>(
      qb, Wa1, ba1, qb, nullptr, nullptr, nullptr, nullptr, nullptr, nullptr);

  // K4: a2 (in-place in ws)
  conv1x1_kernel<false, false, false, 1><<<grid, 256, 0, stream>>>(
      qb, Wa2, ba2, qb, nullptr, nullptr, nullptr, nullptr, nullptr, nullptr);

  // K5: f -> d_out (f32)
  conv1x1_kernel<false, true, false, 1><<<grid, 256, 0, stream>>>(
      qb, Wf, bf_, d_out, nullptr, nullptr, nullptr, nullptr, nullptr, nullptr);
}